// Round 19
// baseline (90.380 us; speedup 1.0000x reference)
//
#include <hip/hip_runtime.h>

// ChamferLoss: B=4, N=M=8192, D=3, fp32.
// loss = mean_b[ mean(pred2gt) + mean(gt2pred) + max(pred2gt) ]
// R27 = R26 resubmitted verbatim (11th infra failure; probe unmeasured).
// R26: ABLATION PROBE (correct output). R25 falsified the AGPR-move theory
//  (asm-VGPR MFMA neutral: 78.5 vs 76.3). Five mechanisms now rejected
//  (occupancy/shape/result-latency/folds/AGPR-moves); bottom-up zero-overlap
//  floor ~14us vs measured nn ~32us -> model missing a 2x. Probe: double
//  EXACTLY the {MFMA+min3} stream (idempotent min; duplicate MFMAs use
//  C=opaque zero2 so CSE can't merge). Staging/ds_read/barriers/epilogue
//  byte-identical to R19 (measured 76.3, absmax 0).
//  Reads (pre-committed): delta>=+15us -> stream-bound -> matrix-overlap
//  occupancy next; delta<=+5us -> stream hidden -> async-split staging next;
//  between -> split probe (double MFMA only). absmax!=0 -> probe broken.
//   A row m (K=16): [xh0..2, xh0..2, xl0,xl1 | xl2, 1, 1, 0...]
//   B col n (K=16): [-2yh0..2, -2yl0..2, -2yh0,-2yh1 | -2yh2, y2h, y2l, 0...]
//   D = y2 - 2(xh.yh + xh.yl + xl.yh); d2 = x2 + min_y D  (xl.yl ~2^-18 dropped)

typedef short  s16x8  __attribute__((ext_vector_type(8)));
typedef float  f32x16 __attribute__((ext_vector_type(16)));

#define BATCH 4
#define NPTS  8192
#define TPB   512                  // 8 waves; 1 block/CU; 2 waves/SIMD
#define XPB   256                  // x per block: 8 waves x 1 tile x 32
#define NXC   (NPTS / XPB)         // 32
#define NPH   4                    // stage phases
#define PHPTS (NPTS / NPH)         // 2048 y-points per phase (64 KB LDS)
#define PHT   (PHPTS / 32)         // 64 y-tiles per phase

__device__ __forceinline__ unsigned int bft(float f) { return __float_as_uint(f) >> 16; }
__device__ __forceinline__ float bfv(unsigned int s) { return __uint_as_float(s << 16); }

__global__ __launch_bounds__(TPB, 2)
void nn_fused(const float* __restrict__ pred, const float* __restrict__ gt,
              float2* __restrict__ partials) {
    const int xc = blockIdx.x, bd = blockIdx.z;
    const int b = bd >> 1, dir = bd & 1;
    const float* xp = (dir ? gt : pred) + (size_t)b * NPTS * 3;
    const float* yp = (dir ? pred : gt) + (size_t)b * NPTS * 3;

    const int t = threadIdx.x;
    const int wv = t >> 6, l = t & 63;
    const int m32 = l & 31, hh = l >> 5;

    // [tile(64)][{0..31: w0(k0-7), 32..63: w1(k8-15)}] per phase = 64 KB
    __shared__ uint4 ldsb[PHT * 64];

    // A-frag + x2 for the wave's single 32-row x-tile.
    const int xi = xc * XPB + wv * 32 + m32;
    const float c0 = xp[xi * 3], c1 = xp[xi * 3 + 1], c2 = xp[xi * 3 + 2];
    const float x2 = c0 * c0 + c1 * c1 + c2 * c2;
    s16x8 af;
    {
        const unsigned int xh0 = bft(c0), xh1 = bft(c1), xh2 = bft(c2);
        const unsigned int xl0 = bft(c0 - bfv(xh0));
        const unsigned int xl1 = bft(c1 - bfv(xh1));
        const unsigned int xl2 = bft(c2 - bfv(xh2));
        af[0] = (short)(hh ? xl2 : xh0);
        af[1] = (short)(hh ? 0x3F80u : xh1);           // 1.0 bf16 (y2h)
        af[2] = (short)(hh ? 0x3F80u : xh2);           // 1.0 bf16 (y2l)
        af[3] = (short)(hh ? 0u : xh0);
        af[4] = (short)(hh ? 0u : xh1);
        af[5] = (short)(hh ? 0u : xh2);
        af[6] = (short)(hh ? 0u : xl0);
        af[7] = (short)(hh ? 0u : xl1);
    }

    f32x16 zero, mn;
    #pragma unroll
    for (int r = 0; r < 16; ++r) { zero[r] = 0.f; mn[r] = 3.4e38f; }

    // Opaque zero: numerically 0 but compiler can't prove it -> duplicate
    // MFMAs (C=zero2) can't be CSE'd with the originals (C=zero).
    float zg = 0.f;
    asm volatile("" : "+v"(zg));
    f32x16 zero2;
    #pragma unroll
    for (int r = 0; r < 16; ++r) zero2[r] = zg;

    const uint4* bp = ldsb + l;                        // lane's fixed k-half slot

#define FOLD(EA, EB)                                                                  \
    do { _Pragma("unroll")                                                            \
         for (int r = 0; r < 16; ++r)                                                 \
             mn[r] = fminf(fminf(mn[r], (EA)[r]), (EB)[r]); } while (0)
#define MFMA(BF)  __builtin_amdgcn_mfma_f32_32x32x16_bf16(af, (BF), zero,  0, 0, 0)
#define MFMA2(BF) __builtin_amdgcn_mfma_f32_32x32x16_bf16(af, (BF), zero2, 0, 0, 0)

    for (int ph = 0; ph < NPH; ++ph) {
        if (ph) __syncthreads();                       // prev-phase reads done
        // Stage 2048 y-points (4/thread) -> packed B-frags in LDS.
        #pragma unroll
        for (int i = 0; i < PHPTS / TPB; ++i) {
            const int q = i * TPB + t;                 // 0..2047 within phase
            const int pt = ph * PHPTS + q;
            const float a0 = yp[pt * 3], a1 = yp[pt * 3 + 1], a2 = yp[pt * 3 + 2];
            const unsigned int yh0 = bft(a0), yh1 = bft(a1), yh2 = bft(a2);
            const float l0 = a0 - bfv(yh0), l1 = a1 - bfv(yh1), l2 = a2 - bfv(yh2);
            const unsigned int nh0 = bft(-2.f * bfv(yh0));  // exact in bf16
            const unsigned int nh1 = bft(-2.f * bfv(yh1));
            const unsigned int nh2 = bft(-2.f * bfv(yh2));
            const unsigned int nl0 = bft(-2.f * l0), nl1 = bft(-2.f * l1), nl2 = bft(-2.f * l2);
            const float y2 = a0 * a0 + a1 * a1 + a2 * a2;
            const unsigned int q2h = bft(y2);
            const unsigned int q2l = bft(y2 - bfv(q2h));
            uint4 w0, w1;
            w0.x = nh0 | (nh1 << 16);
            w0.y = nh2 | (nl0 << 16);
            w0.z = nl1 | (nl2 << 16);
            w0.w = nh0 | (nh1 << 16);
            w1.x = nh2 | (q2h << 16);
            w1.y = q2l;
            w1.z = 0u; w1.w = 0u;
            ldsb[(q >> 5) * 64 + (q & 31)]      = w0;
            ldsb[(q >> 5) * 64 + 32 + (q & 31)] = w1;
        }
        __syncthreads();

        // Hot loop: 64 tiles, R19 ping-pong, every tile-pair MFMA'd + folded
        // TWICE (idempotent; CSE-blocked via zero2).
        f32x16 pA, pB, pA2, pB2, qA, qB, qA2, qB2;
        {
            const s16x8 b0 = __builtin_bit_cast(s16x8, bp[0]);
            const s16x8 b1 = __builtin_bit_cast(s16x8, bp[64]);
            pA = MFMA(b0); pB = MFMA(b1);
            pA2 = MFMA2(b0); pB2 = MFMA2(b1);
        }
        for (int i = 2; i < PHT - 2; i += 4) {
            {
                const s16x8 b0 = __builtin_bit_cast(s16x8, bp[i * 64]);
                const s16x8 b1 = __builtin_bit_cast(s16x8, bp[(i + 1) * 64]);
                qA = MFMA(b0); qB = MFMA(b1);
                qA2 = MFMA2(b0); qB2 = MFMA2(b1);
                FOLD(pA, pB);
                FOLD(pA2, pB2);
            }
            {
                const s16x8 b0 = __builtin_bit_cast(s16x8, bp[(i + 2) * 64]);
                const s16x8 b1 = __builtin_bit_cast(s16x8, bp[(i + 3) * 64]);
                pA = MFMA(b0); pB = MFMA(b1);
                pA2 = MFMA2(b0); pB2 = MFMA2(b1);
                FOLD(qA, qB);
                FOLD(qA2, qB2);
            }
        }
        {   // tail tiles PHT-2, PHT-1
            const s16x8 b0 = __builtin_bit_cast(s16x8, bp[(PHT - 2) * 64]);
            const s16x8 b1 = __builtin_bit_cast(s16x8, bp[(PHT - 1) * 64]);
            qA = MFMA(b0); qB = MFMA(b1);
            qA2 = MFMA2(b0); qB2 = MFMA2(b1);
            FOLD(pA, pB);
            FOLD(pA2, pB2);
            FOLD(qA, qB);
            FOLD(qA2, qB2);
        }
    }
#undef MFMA
#undef MFMA2
#undef FOLD

    // Butterfly min across the 32 cols (stays within each 32-lane half).
    #pragma unroll
    for (int off = 16; off; off >>= 1)
        #pragma unroll
        for (int r = 0; r < 16; ++r)
            mn[r] = fminf(mn[r], __shfl_xor(mn[r], off, 64));

    // Lane l (r = l&15): holds col-min for row (r&3)+8*(r>>2)+4*hh.
    const int r = l & 15;
    const int row = (r & 3) + 8 * (r >> 2) + 4 * hh;   // C/D row map (m74/m101)
    float v = mn[0];
    #pragma unroll
    for (int rr = 1; rr < 16; ++rr) v = (r == rr) ? mn[rr] : v;
    const float x2s = __shfl(x2, row, 64);
    const bool valid = (l & 31) < 16;
    const float d = valid ? fmaxf(v + x2s, 0.f) : 0.f;

    // Block reduction: sum + max over the block's 256 final d's.
    float s = d, m = valid ? d : -1.f;
    #pragma unroll
    for (int off = 32; off; off >>= 1) {
        s += __shfl_xor(s, off, 64);
        m = fmaxf(m, __shfl_xor(m, off, 64));
    }
    __shared__ float ws_[8], wm_[8];
    if (l == 0) { ws_[wv] = s; wm_[wv] = m; }
    __syncthreads();
    if (t == 0) {
        float bs = 0.f, bm = -1.f;
        #pragma unroll
        for (int i = 0; i < 8; ++i) { bs += ws_[i]; bm = fmaxf(bm, wm_[i]); }
        partials[bd * NXC + xc] = make_float2(bs, bm);
    }
}

// One block, 256 threads: t -> (bd = t>>5, xc = t&31). Reduce 32 partials per
// bd within each 32-lane group, then thread 0 combines 8 bd's.
__global__ __launch_bounds__(256)
void reduce_all(const float2* __restrict__ partials, float* __restrict__ out) {
    const int t = threadIdx.x;
    const float2 p = partials[t];
    float s = p.x, m = p.y;
    #pragma unroll
    for (int off = 16; off; off >>= 1) {               // stays within 32-group
        s += __shfl_xor(s, off, 64);
        m = fmaxf(m, __shfl_xor(m, off, 64));
    }
    __shared__ float s8[8], m8[8];
    if ((t & 31) == 0) { s8[t >> 5] = s; m8[t >> 5] = m; }
    __syncthreads();
    if (t == 0) {
        float acc = 0.f;
        #pragma unroll
        for (int b2 = 0; b2 < BATCH; ++b2)
            acc += (s8[2 * b2] + s8[2 * b2 + 1]) * (1.f / NPTS)
                 + m8[2 * b2];                         // max only for pred2gt
        out[0] = acc * (1.f / BATCH);
    }
}

extern "C" void kernel_launch(void* const* d_in, const int* in_sizes, int n_in,
                              void* d_out, int out_size, void* d_ws, size_t ws_size,
                              hipStream_t stream) {
    const float* pred = (const float*)d_in[0];
    const float* gt   = (const float*)d_in[1];

    float2* partials = (float2*)d_ws;                  // 256 * 8 B = 2 KB

    dim3 g1(NXC, 1, 2 * BATCH);    // 32 x 1 x 8 = 256 blocks (1/CU)
    nn_fused<<<g1, TPB, 0, stream>>>(pred, gt, partials);
    reduce_all<<<dim3(1), 256, 0, stream>>>(partials, (float*)d_out);
}

// Round 21
// 81.287 us; speedup vs baseline: 1.1119x; 1.1119x over previous
//
#include <hip/hip_runtime.h>

// ChamferLoss: B=4, N=M=8192, D=3, fp32.
// loss = mean_b[ mean(pred2gt) + mean(gt2pred) + max(pred2gt) ]
// R29 = R28 resubmitted verbatim ("container failed twice" = infra; the same
//  error hit R23's submission which later ran clean as R25. R28 has no asm,
//  128KB/CU LDS at 2 blocks/CU, proven epilogue -> nothing kernel-side).
// R28: OCCUPANCY fix, driven by the R27 probe counters (first full nn PMC):
//  doubled {MFMA+min3} cost exactly +1x compute-issue time (Δ+10us ~= 10.4us
//  serialized) on top of a ~20us latency floor; VALUBusy 42% matches UNFUSED
//  v_min count; Occupancy 18.8% = 1 block/CU = 2 waves/SIMD -> zero cross-
//  stream overlap. Fix: YS=2 -> 512 blocks = 2 blocks/CU = 4 waves/SIMD.
//  Budget at 4 waves/SIMD is 128 unified regs -> single-pair-in-flight with
//  immediate folds (acc 64 + ~45 VGPR ~= 109); TLP replaces the ping-pong.
//  Cost: per-point min over 2 slices -> pmin (512KB) + R15's atomic reduce.
//  v_min3 asm deliberately deferred (keep round single-variable).
//   A row m (K=16): [xh0..2, xh0..2, xl0,xl1 | xl2, 1, 1, 0...]
//   B col n (K=16): [-2yh0..2, -2yl0..2, -2yh0,-2yh1 | -2yh2, y2h, y2l, 0...]
//   D = y2 - 2(xh.yh + xh.yl + xl.yh); d2 = x2 + min_y D  (xl.yl ~2^-18 dropped)

typedef short  s16x8  __attribute__((ext_vector_type(8)));
typedef float  f32x16 __attribute__((ext_vector_type(16)));

#define BATCH 4
#define NPTS  8192
#define TPB   512                  // 8 waves
#define XPB   256                  // x per block: 8 waves x 1 tile x 32
#define NXC   (NPTS / XPB)         // 32
#define YS    2                    // y slices -> 512 blocks = 2 blocks/CU
#define YPS   (NPTS / YS)          // 4096 y-points per slice
#define PHPTS 2048                 // y-points per phase (64 KB LDS)
#define NPH   (YPS / PHPTS)        // 2 phases
#define PHT   (PHPTS / 32)         // 64 y-tiles per phase
#define RBLK  64                   // reduce blocks

__device__ __forceinline__ unsigned int bft(float f) { return __float_as_uint(f) >> 16; }
__device__ __forceinline__ float bfv(unsigned int s) { return __uint_as_float(s << 16); }

__global__ __launch_bounds__(TPB, 4)
void nn_fused(const float* __restrict__ pred, const float* __restrict__ gt,
              float* __restrict__ pmin, unsigned int* __restrict__ accum) {
    const int xc = blockIdx.x, sl = blockIdx.y, bd = blockIdx.z;
    const int t = threadIdx.x;
    // Zero reduce accumulators (8 sums + 8 maxbits + counter); stream-ordered.
    if (xc == 0 && sl == 0 && bd == 0 && t < 17) accum[t] = 0u;

    const int b = bd >> 1, dir = bd & 1;
    const float* xp = (dir ? gt : pred) + (size_t)b * NPTS * 3;
    const float* yp = (dir ? pred : gt) + (size_t)b * NPTS * 3;

    const int wv = t >> 6, l = t & 63;
    const int m32 = l & 31, hh = l >> 5;

    // [tile(64)][{0..31: w0(k0-7), 32..63: w1(k8-15)}] per phase = 64 KB
    __shared__ uint4 ldsb[PHT * 64];

    // A-frag + x2 for the wave's single 32-row x-tile.
    const int xi = xc * XPB + wv * 32 + m32;
    const float c0 = xp[xi * 3], c1 = xp[xi * 3 + 1], c2 = xp[xi * 3 + 2];
    const float x2 = c0 * c0 + c1 * c1 + c2 * c2;
    s16x8 af;
    {
        const unsigned int xh0 = bft(c0), xh1 = bft(c1), xh2 = bft(c2);
        const unsigned int xl0 = bft(c0 - bfv(xh0));
        const unsigned int xl1 = bft(c1 - bfv(xh1));
        const unsigned int xl2 = bft(c2 - bfv(xh2));
        af[0] = (short)(hh ? xl2 : xh0);
        af[1] = (short)(hh ? 0x3F80u : xh1);           // 1.0 bf16 (y2h)
        af[2] = (short)(hh ? 0x3F80u : xh2);           // 1.0 bf16 (y2l)
        af[3] = (short)(hh ? 0u : xh0);
        af[4] = (short)(hh ? 0u : xh1);
        af[5] = (short)(hh ? 0u : xh2);
        af[6] = (short)(hh ? 0u : xl0);
        af[7] = (short)(hh ? 0u : xl1);
    }

    f32x16 zero, mn;
    #pragma unroll
    for (int r = 0; r < 16; ++r) { zero[r] = 0.f; mn[r] = 3.4e38f; }

    const uint4* bp = ldsb + l;                        // lane's fixed k-half slot

    for (int ph = 0; ph < NPH; ++ph) {
        if (ph) __syncthreads();                       // prev-phase reads done
        // Stage 2048 y-points (4/thread) -> packed B-frags in LDS.
        #pragma unroll
        for (int i = 0; i < PHPTS / TPB; ++i) {
            const int q = i * TPB + t;                 // 0..2047 within phase
            const int pt = sl * YPS + ph * PHPTS + q;
            const float a0 = yp[pt * 3], a1 = yp[pt * 3 + 1], a2 = yp[pt * 3 + 2];
            const unsigned int yh0 = bft(a0), yh1 = bft(a1), yh2 = bft(a2);
            const float l0 = a0 - bfv(yh0), l1 = a1 - bfv(yh1), l2 = a2 - bfv(yh2);
            const unsigned int nh0 = bft(-2.f * bfv(yh0));  // exact in bf16
            const unsigned int nh1 = bft(-2.f * bfv(yh1));
            const unsigned int nh2 = bft(-2.f * bfv(yh2));
            const unsigned int nl0 = bft(-2.f * l0), nl1 = bft(-2.f * l1), nl2 = bft(-2.f * l2);
            const float y2 = a0 * a0 + a1 * a1 + a2 * a2;
            const unsigned int q2h = bft(y2);
            const unsigned int q2l = bft(y2 - bfv(q2h));
            uint4 w0, w1;
            w0.x = nh0 | (nh1 << 16);
            w0.y = nh2 | (nl0 << 16);
            w0.z = nl1 | (nl2 << 16);
            w0.w = nh0 | (nh1 << 16);
            w1.x = nh2 | (q2h << 16);
            w1.y = q2l;
            w1.z = 0u; w1.w = 0u;
            ldsb[(q >> 5) * 64 + (q & 31)]      = w0;
            ldsb[(q >> 5) * 64 + 32 + (q & 31)] = w1;
        }
        __syncthreads();

        // Hot loop: 64 tiles, single pair in flight, immediate fold.
        // 4 waves/SIMD provide the latency cover the R19 ping-pong bought
        // with registers.
        for (int i = 0; i < PHT; i += 2) {
            const s16x8 b0 = __builtin_bit_cast(s16x8, bp[i * 64]);
            const s16x8 b1 = __builtin_bit_cast(s16x8, bp[(i + 1) * 64]);
            const f32x16 e0 = __builtin_amdgcn_mfma_f32_32x32x16_bf16(af, b0, zero, 0, 0, 0);
            const f32x16 e1 = __builtin_amdgcn_mfma_f32_32x32x16_bf16(af, b1, zero, 0, 0, 0);
            #pragma unroll
            for (int r = 0; r < 16; ++r)
                mn[r] = fminf(fminf(mn[r], e0[r]), e1[r]);
        }
    }

    // Butterfly min across the 32 cols (stays within each 32-lane half).
    #pragma unroll
    for (int off = 16; off; off >>= 1)
        #pragma unroll
        for (int r = 0; r < 16; ++r)
            mn[r] = fminf(mn[r], __shfl_xor(mn[r], off, 64));

    // Lane l (r = l&15): holds col-min for row (r&3)+8*(r>>2)+4*hh.
    const int r = l & 15;
    const int row = (r & 3) + 8 * (r >> 2) + 4 * hh;   // C/D row map (m74/m101)
    float v = mn[0];
    #pragma unroll
    for (int rr = 1; rr < 16; ++rr) v = (r == rr) ? mn[rr] : v;
    const float x2s = __shfl(x2, row, 64);
    if ((l & 31) < 16) {
        const float d = fmaxf(v + x2s, 0.f);
        const int xpt = xc * XPB + wv * 32 + row;
        pmin[((size_t)bd * YS + sl) * NPTS + xpt] = d;  // unique writer
    }
}

// 64 blocks x 256 threads. Block g: bd = g>>3, x-segment = g&7 (1024 pts).
// Min over YS slices, partial sum+max -> device atomics; last block finalizes.
// accum: [0..7] f32 sums, [8..15] u32 maxbits, [16] counter.
__global__ __launch_bounds__(256)
void reduce_all(const float* __restrict__ pmin, float* __restrict__ accum,
                float* __restrict__ out) {
    const int g = blockIdx.x, bd = g >> 3, seg = g & 7;
    const int t = threadIdx.x;
    const float4* base = (const float4*)(pmin + (size_t)bd * YS * NPTS);
    const int f4 = seg * 256 + t;                      // float4 idx within slice
    float4 q = base[f4];
    #pragma unroll
    for (int sl = 1; sl < YS; ++sl) {
        const float4 rr = base[sl * (NPTS / 4) + f4];
        q.x = fminf(q.x, rr.x); q.y = fminf(q.y, rr.y);
        q.z = fminf(q.z, rr.z); q.w = fminf(q.w, rr.w);
    }
    float s = (q.x + q.y) + (q.z + q.w);
    float m = fmaxf(fmaxf(q.x, q.y), fmaxf(q.z, q.w));
    #pragma unroll
    for (int off = 32; off; off >>= 1) {
        s += __shfl_down(s, off, 64);
        m = fmaxf(m, __shfl_down(m, off, 64));
    }
    __shared__ float ws_[4], wm_[4];
    if ((t & 63) == 0) { ws_[t >> 6] = s; wm_[t >> 6] = m; }
    __syncthreads();
    if (t == 0) {
        s = (ws_[0] + ws_[1]) + (ws_[2] + ws_[3]);
        m = fmaxf(fmaxf(wm_[0], wm_[1]), fmaxf(wm_[2], wm_[3]));
        atomicAdd(&accum[bd], s);
        atomicMax((unsigned int*)accum + 8 + bd, __float_as_uint(m));  // d>=0
        __threadfence();
        const unsigned int done = atomicAdd((unsigned int*)accum + 16, 1u);
        if (done == RBLK - 1) {
            float acc = 0.f;
            #pragma unroll
            for (int b2 = 0; b2 < BATCH; ++b2) {
                const float s0 = atomicAdd(&accum[2 * b2], 0.f);      // coherent read
                const float s1 = atomicAdd(&accum[2 * b2 + 1], 0.f);
                const unsigned int mb =
                    atomicMax((unsigned int*)accum + 8 + 2 * b2, 0u); // pred2gt max
                acc += (s0 + s1) * (1.f / NPTS) + __uint_as_float(mb);
            }
            out[0] = acc * (1.f / BATCH);
        }
    }
}

extern "C" void kernel_launch(void* const* d_in, const int* in_sizes, int n_in,
                              void* d_out, int out_size, void* d_ws, size_t ws_size,
                              hipStream_t stream) {
    const float* pred = (const float*)d_in[0];
    const float* gt   = (const float*)d_in[1];

    float* pmin = (float*)d_ws;                        // 8 * 2 * 8192 * 4B = 512 KB
    float* accum = (float*)((char*)d_ws + (size_t)2 * BATCH * YS * NPTS * 4);

    dim3 g1(NXC, YS, 2 * BATCH);   // 32 x 2 x 8 = 512 blocks (2/CU)
    nn_fused<<<g1, TPB, 0, stream>>>(pred, gt, pmin, (unsigned int*)accum);
    reduce_all<<<dim3(RBLK), 256, 0, stream>>>(pmin, accum, (float*)d_out);
}

// Round 23
// 78.232 us; speedup vs baseline: 1.1553x; 1.0390x over previous
//
#include <hip/hip_runtime.h>

// ChamferLoss: B=4, N=M=8192, D=3, fp32.
// loss = mean_b[ mean(pred2gt) + mean(gt2pred) + max(pred2gt) ]
// R31 = R30 resubmitted verbatim (13th infra failure; unmeasured).
// R30 = R19 base (best measured, 76.3us) + v_min3 asm folds. Evidence chain:
//  R27 probe: doubling {MFMA+min3} adds its full serialized issue time
//  (+10us) -> compute stream is on the critical path; VALUBusy 42% matches
//  the UNFUSED v_min count (fminf(fminf()) does NOT fuse to v_min3).
//  R29: YS=2 (2 blocks/CU, 4 waves/SIMD) NEUTRAL -> floor is per-CU-
//  saturated, not per-wave latency; TLP can't dent it -> REVERTED.
//  This round: halve the fold stream via inline v_min3_f32 (VOP3, all-VGPR,
//  VALU interlocked, no NaN inputs): 4096 v_min -> 2048 v_min3 per wave,
//  ~-3.4us serialized issue. Single variable vs R19.
//  Fixed ~40.5us harness ws-poison fill is included in dur_us.
//   A row m (K=16): [xh0..2, xh0..2, xl0,xl1 | xl2, 1, 1, 0...]
//   B col n (K=16): [-2yh0..2, -2yl0..2, -2yh0,-2yh1 | -2yh2, y2h, y2l, 0...]
//   D = y2 - 2(xh.yh + xh.yl + xl.yh); d2 = x2 + min_y D  (xl.yl ~2^-18 dropped)

typedef short  s16x8  __attribute__((ext_vector_type(8)));
typedef float  f32x16 __attribute__((ext_vector_type(16)));

#define BATCH 4
#define NPTS  8192
#define TPB   512                  // 8 waves; 1 block/CU; 2 waves/SIMD
#define XPB   256                  // x per block: 8 waves x 1 tile x 32
#define NXC   (NPTS / XPB)         // 32
#define NPH   4                    // stage phases
#define PHPTS (NPTS / NPH)         // 2048 y-points per phase (64 KB LDS)
#define PHT   (PHPTS / 32)         // 64 y-tiles per phase

__device__ __forceinline__ unsigned int bft(float f) { return __float_as_uint(f) >> 16; }
__device__ __forceinline__ float bfv(unsigned int s) { return __uint_as_float(s << 16); }

// 3-input min in one VALU op (compiler verifiably does NOT fuse fminf chains
// here -- R27 probe: VALUBusy matches unfused count).
__device__ __forceinline__ float min3f(float a, float b, float c) {
    float d;
    asm("v_min3_f32 %0, %1, %2, %3" : "=v"(d) : "v"(a), "v"(b), "v"(c));
    return d;
}

__global__ __launch_bounds__(TPB, 2)
void nn_fused(const float* __restrict__ pred, const float* __restrict__ gt,
              float2* __restrict__ partials) {
    const int xc = blockIdx.x, bd = blockIdx.z;
    const int b = bd >> 1, dir = bd & 1;
    const float* xp = (dir ? gt : pred) + (size_t)b * NPTS * 3;
    const float* yp = (dir ? pred : gt) + (size_t)b * NPTS * 3;

    const int t = threadIdx.x;
    const int wv = t >> 6, l = t & 63;
    const int m32 = l & 31, hh = l >> 5;

    // [tile(64)][{0..31: w0(k0-7), 32..63: w1(k8-15)}] per phase = 64 KB
    __shared__ uint4 ldsb[PHT * 64];

    // A-frag + x2 for the wave's single 32-row x-tile.
    const int xi = xc * XPB + wv * 32 + m32;
    const float c0 = xp[xi * 3], c1 = xp[xi * 3 + 1], c2 = xp[xi * 3 + 2];
    const float x2 = c0 * c0 + c1 * c1 + c2 * c2;
    s16x8 af;
    {
        const unsigned int xh0 = bft(c0), xh1 = bft(c1), xh2 = bft(c2);
        const unsigned int xl0 = bft(c0 - bfv(xh0));
        const unsigned int xl1 = bft(c1 - bfv(xh1));
        const unsigned int xl2 = bft(c2 - bfv(xh2));
        af[0] = (short)(hh ? xl2 : xh0);
        af[1] = (short)(hh ? 0x3F80u : xh1);           // 1.0 bf16 (y2h)
        af[2] = (short)(hh ? 0x3F80u : xh2);           // 1.0 bf16 (y2l)
        af[3] = (short)(hh ? 0u : xh0);
        af[4] = (short)(hh ? 0u : xh1);
        af[5] = (short)(hh ? 0u : xh2);
        af[6] = (short)(hh ? 0u : xl0);
        af[7] = (short)(hh ? 0u : xl1);
    }

    f32x16 zero, mn;
    #pragma unroll
    for (int r = 0; r < 16; ++r) { zero[r] = 0.f; mn[r] = 3.4e38f; }

    const uint4* bp = ldsb + l;                        // lane's fixed k-half slot

#define FOLD(EA, EB)                                                                  \
    do { _Pragma("unroll")                                                            \
         for (int r = 0; r < 16; ++r)                                                 \
             mn[r] = min3f(mn[r], (EA)[r], (EB)[r]); } while (0)
#define MFMA(BF) __builtin_amdgcn_mfma_f32_32x32x16_bf16(af, (BF), zero, 0, 0, 0)

    for (int ph = 0; ph < NPH; ++ph) {
        if (ph) __syncthreads();                       // prev-phase reads done
        // Stage 2048 y-points (4/thread) -> packed B-frags in LDS.
        #pragma unroll
        for (int i = 0; i < PHPTS / TPB; ++i) {
            const int q = i * TPB + t;                 // 0..2047 within phase
            const int pt = ph * PHPTS + q;
            const float a0 = yp[pt * 3], a1 = yp[pt * 3 + 1], a2 = yp[pt * 3 + 2];
            const unsigned int yh0 = bft(a0), yh1 = bft(a1), yh2 = bft(a2);
            const float l0 = a0 - bfv(yh0), l1 = a1 - bfv(yh1), l2 = a2 - bfv(yh2);
            const unsigned int nh0 = bft(-2.f * bfv(yh0));  // exact in bf16
            const unsigned int nh1 = bft(-2.f * bfv(yh1));
            const unsigned int nh2 = bft(-2.f * bfv(yh2));
            const unsigned int nl0 = bft(-2.f * l0), nl1 = bft(-2.f * l1), nl2 = bft(-2.f * l2);
            const float y2 = a0 * a0 + a1 * a1 + a2 * a2;
            const unsigned int q2h = bft(y2);
            const unsigned int q2l = bft(y2 - bfv(q2h));
            uint4 w0, w1;
            w0.x = nh0 | (nh1 << 16);
            w0.y = nh2 | (nl0 << 16);
            w0.z = nl1 | (nl2 << 16);
            w0.w = nh0 | (nh1 << 16);
            w1.x = nh2 | (q2h << 16);
            w1.y = q2l;
            w1.z = 0u; w1.w = 0u;
            ldsb[(q >> 5) * 64 + (q & 31)]      = w0;
            ldsb[(q >> 5) * 64 + 32 + (q & 31)] = w1;
        }
        __syncthreads();

        // Hot loop: 64 tiles, one-pair-behind fold (ping-pong, no rotate).
        f32x16 pA, pB, qA, qB;
        {
            const s16x8 b0 = __builtin_bit_cast(s16x8, bp[0]);
            const s16x8 b1 = __builtin_bit_cast(s16x8, bp[64]);
            pA = MFMA(b0); pB = MFMA(b1);
        }
        for (int i = 2; i < PHT - 2; i += 4) {
            {
                const s16x8 b0 = __builtin_bit_cast(s16x8, bp[i * 64]);
                const s16x8 b1 = __builtin_bit_cast(s16x8, bp[(i + 1) * 64]);
                qA = MFMA(b0); qB = MFMA(b1);
                FOLD(pA, pB);                          // results >=2 MFMAs old
            }
            {
                const s16x8 b0 = __builtin_bit_cast(s16x8, bp[(i + 2) * 64]);
                const s16x8 b1 = __builtin_bit_cast(s16x8, bp[(i + 3) * 64]);
                pA = MFMA(b0); pB = MFMA(b1);
                FOLD(qA, qB);
            }
        }
        {   // tail tiles PHT-2, PHT-1
            const s16x8 b0 = __builtin_bit_cast(s16x8, bp[(PHT - 2) * 64]);
            const s16x8 b1 = __builtin_bit_cast(s16x8, bp[(PHT - 1) * 64]);
            qA = MFMA(b0); qB = MFMA(b1);
            FOLD(pA, pB);
            FOLD(qA, qB);
        }
    }
#undef MFMA
#undef FOLD

    // Butterfly min across the 32 cols (stays within each 32-lane half).
    #pragma unroll
    for (int off = 16; off; off >>= 1)
        #pragma unroll
        for (int r = 0; r < 16; ++r)
            mn[r] = fminf(mn[r], __shfl_xor(mn[r], off, 64));

    // Lane l (r = l&15): holds col-min for row (r&3)+8*(r>>2)+4*hh.
    const int r = l & 15;
    const int row = (r & 3) + 8 * (r >> 2) + 4 * hh;   // C/D row map (m74/m101)
    float v = mn[0];
    #pragma unroll
    for (int rr = 1; rr < 16; ++rr) v = (r == rr) ? mn[rr] : v;
    const float x2s = __shfl(x2, row, 64);
    const bool valid = (l & 31) < 16;
    const float d = valid ? fmaxf(v + x2s, 0.f) : 0.f;

    // Block reduction: sum + max over the block's 256 final d's.
    float s = d, m = valid ? d : -1.f;
    #pragma unroll
    for (int off = 32; off; off >>= 1) {
        s += __shfl_xor(s, off, 64);
        m = fmaxf(m, __shfl_xor(m, off, 64));
    }
    __shared__ float ws_[8], wm_[8];
    if (l == 0) { ws_[wv] = s; wm_[wv] = m; }
    __syncthreads();
    if (t == 0) {
        float bs = 0.f, bm = -1.f;
        #pragma unroll
        for (int i = 0; i < 8; ++i) { bs += ws_[i]; bm = fmaxf(bm, wm_[i]); }
        partials[bd * NXC + xc] = make_float2(bs, bm);
    }
}

// One block, 256 threads: t -> (bd = t>>5, xc = t&31). Reduce 32 partials per
// bd within each 32-lane group, then thread 0 combines 8 bd's.
__global__ __launch_bounds__(256)
void reduce_all(const float2* __restrict__ partials, float* __restrict__ out) {
    const int t = threadIdx.x;
    const float2 p = partials[t];
    float s = p.x, m = p.y;
    #pragma unroll
    for (int off = 16; off; off >>= 1) {               // stays within 32-group
        s += __shfl_xor(s, off, 64);
        m = fmaxf(m, __shfl_xor(m, off, 64));
    }
    __shared__ float s8[8], m8[8];
    if ((t & 31) == 0) { s8[t >> 5] = s; m8[t >> 5] = m; }
    __syncthreads();
    if (t == 0) {
        float acc = 0.f;
        #pragma unroll
        for (int b2 = 0; b2 < BATCH; ++b2)
            acc += (s8[2 * b2] + s8[2 * b2 + 1]) * (1.f / NPTS)
                 + m8[2 * b2];                         // max only for pred2gt
        out[0] = acc * (1.f / BATCH);
    }
}

extern "C" void kernel_launch(void* const* d_in, const int* in_sizes, int n_in,
                              void* d_out, int out_size, void* d_ws, size_t ws_size,
                              hipStream_t stream) {
    const float* pred = (const float*)d_in[0];
    const float* gt   = (const float*)d_in[1];

    float2* partials = (float2*)d_ws;                  // 256 * 8 B = 2 KB

    dim3 g1(NXC, 1, 2 * BATCH);    // 32 x 1 x 8 = 256 blocks (1/CU)
    nn_fused<<<g1, TPB, 0, stream>>>(pred, gt, partials);
    reduce_all<<<dim3(1), 256, 0, stream>>>(partials, (float*)d_out);
}

// Round 24
// 75.180 us; speedup vs baseline: 1.2022x; 1.0406x over previous
//
#include <hip/hip_runtime.h>

// ChamferLoss: B=4, N=M=8192, D=3, fp32.
// loss = mean_b[ mean(pred2gt) + mean(gt2pred) + max(pred2gt) ]
// R32 = R19 exact (best measured 76.3us) + async-stage split (T14): next
//  phase's raw-y loads issued into regs BEFORE the hot loop, consumed at next
//  staging -> phase-boundary global latency hides under ~7us of compute.
// Model (reconciled, R27 counters + corrected 32.3 cyc/SIMD MFMA):
//  nn ~30us = 6.6 MFMA + ~9.4 VALU + ~14 stall. R31 (v_min3, -3.4us VALU)
//  neutral -> VALU absorbed by stall, not critical. R12(16w/CU, half LDS
//  reads) == R19(8w/CU) -> stall is not LDS-throughput/wave-count; it's
//  lockstep-phase latency. This round targets the phase-boundary load slice.
//  Falsified to date: occupancy(R16/R29), 16x16 shape(R17), result-latency
//  pipelining(R19), fold trees(R14), AGPR moves(R25), TLP(R29), min3(R31).
//   A row m (K=16): [xh0..2, xh0..2, xl0,xl1 | xl2, 1, 1, 0...]
//   B col n (K=16): [-2yh0..2, -2yl0..2, -2yh0,-2yh1 | -2yh2, y2h, y2l, 0...]
//   D = y2 - 2(xh.yh + xh.yl + xl.yh); d2 = x2 + min_y D  (xl.yl ~2^-18 dropped)

typedef short  s16x8  __attribute__((ext_vector_type(8)));
typedef float  f32x16 __attribute__((ext_vector_type(16)));

#define BATCH 4
#define NPTS  8192
#define TPB   512                  // 8 waves; 1 block/CU; 2 waves/SIMD
#define XPB   256                  // x per block: 8 waves x 1 tile x 32
#define NXC   (NPTS / XPB)         // 32
#define NPH   4                    // stage phases
#define PHPTS (NPTS / NPH)         // 2048 y-points per phase (64 KB LDS)
#define PHT   (PHPTS / 32)         // 64 y-tiles per phase
#define PPT   (PHPTS / TPB)        // 4 points per thread per phase

__device__ __forceinline__ unsigned int bft(float f) { return __float_as_uint(f) >> 16; }
__device__ __forceinline__ float bfv(unsigned int s) { return __uint_as_float(s << 16); }

__global__ __launch_bounds__(TPB, 2)
void nn_fused(const float* __restrict__ pred, const float* __restrict__ gt,
              float2* __restrict__ partials) {
    const int xc = blockIdx.x, bd = blockIdx.z;
    const int b = bd >> 1, dir = bd & 1;
    const float* xp = (dir ? gt : pred) + (size_t)b * NPTS * 3;
    const float* yp = (dir ? pred : gt) + (size_t)b * NPTS * 3;

    const int t = threadIdx.x;
    const int wv = t >> 6, l = t & 63;
    const int m32 = l & 31, hh = l >> 5;

    // [tile(64)][{0..31: w0(k0-7), 32..63: w1(k8-15)}] per phase = 64 KB
    __shared__ uint4 ldsb[PHT * 64];

    // A-frag + x2 for the wave's single 32-row x-tile.
    const int xi = xc * XPB + wv * 32 + m32;
    const float c0 = xp[xi * 3], c1 = xp[xi * 3 + 1], c2 = xp[xi * 3 + 2];
    const float x2 = c0 * c0 + c1 * c1 + c2 * c2;
    s16x8 af;
    {
        const unsigned int xh0 = bft(c0), xh1 = bft(c1), xh2 = bft(c2);
        const unsigned int xl0 = bft(c0 - bfv(xh0));
        const unsigned int xl1 = bft(c1 - bfv(xh1));
        const unsigned int xl2 = bft(c2 - bfv(xh2));
        af[0] = (short)(hh ? xl2 : xh0);
        af[1] = (short)(hh ? 0x3F80u : xh1);           // 1.0 bf16 (y2h)
        af[2] = (short)(hh ? 0x3F80u : xh2);           // 1.0 bf16 (y2l)
        af[3] = (short)(hh ? 0u : xh0);
        af[4] = (short)(hh ? 0u : xh1);
        af[5] = (short)(hh ? 0u : xh2);
        af[6] = (short)(hh ? 0u : xl0);
        af[7] = (short)(hh ? 0u : xl1);
    }

    f32x16 zero, mn;
    #pragma unroll
    for (int r = 0; r < 16; ++r) { zero[r] = 0.f; mn[r] = 3.4e38f; }

    const uint4* bp = ldsb + l;                        // lane's fixed k-half slot

    // Raw-y register buffer for the async-stage split (12 floats/thread).
    float ry[PPT][3];
    #pragma unroll
    for (int i = 0; i < PPT; ++i) {                    // phase-0 loads
        const int pt = i * TPB + t;
        ry[i][0] = yp[pt * 3]; ry[i][1] = yp[pt * 3 + 1]; ry[i][2] = yp[pt * 3 + 2];
    }

#define FOLD(EA, EB)                                                                  \
    do { _Pragma("unroll")                                                            \
         for (int r = 0; r < 16; ++r)                                                 \
             mn[r] = fminf(fminf(mn[r], (EA)[r]), (EB)[r]); } while (0)
#define MFMA(BF) __builtin_amdgcn_mfma_f32_32x32x16_bf16(af, (BF), zero, 0, 0, 0)

    for (int ph = 0; ph < NPH; ++ph) {
        if (ph) __syncthreads();                       // prev-phase reads done
        // Stage from registers: frag math + LDS writes only (loads already done).
        #pragma unroll
        for (int i = 0; i < PPT; ++i) {
            const int q = i * TPB + t;                 // 0..2047 within phase
            const float a0 = ry[i][0], a1 = ry[i][1], a2 = ry[i][2];
            const unsigned int yh0 = bft(a0), yh1 = bft(a1), yh2 = bft(a2);
            const float l0 = a0 - bfv(yh0), l1 = a1 - bfv(yh1), l2 = a2 - bfv(yh2);
            const unsigned int nh0 = bft(-2.f * bfv(yh0));  // exact in bf16
            const unsigned int nh1 = bft(-2.f * bfv(yh1));
            const unsigned int nh2 = bft(-2.f * bfv(yh2));
            const unsigned int nl0 = bft(-2.f * l0), nl1 = bft(-2.f * l1), nl2 = bft(-2.f * l2);
            const float y2 = a0 * a0 + a1 * a1 + a2 * a2;
            const unsigned int q2h = bft(y2);
            const unsigned int q2l = bft(y2 - bfv(q2h));
            uint4 w0, w1;
            w0.x = nh0 | (nh1 << 16);
            w0.y = nh2 | (nl0 << 16);
            w0.z = nl1 | (nl2 << 16);
            w0.w = nh0 | (nh1 << 16);
            w1.x = nh2 | (q2h << 16);
            w1.y = q2l;
            w1.z = 0u; w1.w = 0u;
            ldsb[(q >> 5) * 64 + (q & 31)]      = w0;
            ldsb[(q >> 5) * 64 + 32 + (q & 31)] = w1;
        }
        // Issue next phase's loads NOW; they complete under the hot loop.
        if (ph + 1 < NPH) {
            #pragma unroll
            for (int i = 0; i < PPT; ++i) {
                const int pt = (ph + 1) * PHPTS + i * TPB + t;
                ry[i][0] = yp[pt * 3]; ry[i][1] = yp[pt * 3 + 1]; ry[i][2] = yp[pt * 3 + 2];
            }
        }
        __syncthreads();

        // Hot loop: 64 tiles, one-pair-behind fold (ping-pong, no rotate).
        f32x16 pA, pB, qA, qB;
        {
            const s16x8 b0 = __builtin_bit_cast(s16x8, bp[0]);
            const s16x8 b1 = __builtin_bit_cast(s16x8, bp[64]);
            pA = MFMA(b0); pB = MFMA(b1);
        }
        for (int i = 2; i < PHT - 2; i += 4) {
            {
                const s16x8 b0 = __builtin_bit_cast(s16x8, bp[i * 64]);
                const s16x8 b1 = __builtin_bit_cast(s16x8, bp[(i + 1) * 64]);
                qA = MFMA(b0); qB = MFMA(b1);
                FOLD(pA, pB);                          // results >=2 MFMAs old
            }
            {
                const s16x8 b0 = __builtin_bit_cast(s16x8, bp[(i + 2) * 64]);
                const s16x8 b1 = __builtin_bit_cast(s16x8, bp[(i + 3) * 64]);
                pA = MFMA(b0); pB = MFMA(b1);
                FOLD(qA, qB);
            }
        }
        {   // tail tiles PHT-2, PHT-1
            const s16x8 b0 = __builtin_bit_cast(s16x8, bp[(PHT - 2) * 64]);
            const s16x8 b1 = __builtin_bit_cast(s16x8, bp[(PHT - 1) * 64]);
            qA = MFMA(b0); qB = MFMA(b1);
            FOLD(pA, pB);
            FOLD(qA, qB);
        }
    }
#undef MFMA
#undef FOLD

    // Butterfly min across the 32 cols (stays within each 32-lane half).
    #pragma unroll
    for (int off = 16; off; off >>= 1)
        #pragma unroll
        for (int r = 0; r < 16; ++r)
            mn[r] = fminf(mn[r], __shfl_xor(mn[r], off, 64));

    // Lane l (r = l&15): holds col-min for row (r&3)+8*(r>>2)+4*hh.
    const int r = l & 15;
    const int row = (r & 3) + 8 * (r >> 2) + 4 * hh;   // C/D row map (m74/m101)
    float v = mn[0];
    #pragma unroll
    for (int rr = 1; rr < 16; ++rr) v = (r == rr) ? mn[rr] : v;
    const float x2s = __shfl(x2, row, 64);
    const bool valid = (l & 31) < 16;
    const float d = valid ? fmaxf(v + x2s, 0.f) : 0.f;

    // Block reduction: sum + max over the block's 256 final d's.
    float s = d, m = valid ? d : -1.f;
    #pragma unroll
    for (int off = 32; off; off >>= 1) {
        s += __shfl_xor(s, off, 64);
        m = fmaxf(m, __shfl_xor(m, off, 64));
    }
    __shared__ float ws_[8], wm_[8];
    if (l == 0) { ws_[wv] = s; wm_[wv] = m; }
    __syncthreads();
    if (t == 0) {
        float bs = 0.f, bm = -1.f;
        #pragma unroll
        for (int i = 0; i < 8; ++i) { bs += ws_[i]; bm = fmaxf(bm, wm_[i]); }
        partials[bd * NXC + xc] = make_float2(bs, bm);
    }
}

// One block, 256 threads: t -> (bd = t>>5, xc = t&31). Reduce 32 partials per
// bd within each 32-lane group, then thread 0 combines 8 bd's.
__global__ __launch_bounds__(256)
void reduce_all(const float2* __restrict__ partials, float* __restrict__ out) {
    const int t = threadIdx.x;
    const float2 p = partials[t];
    float s = p.x, m = p.y;
    #pragma unroll
    for (int off = 16; off; off >>= 1) {               // stays within 32-group
        s += __shfl_xor(s, off, 64);
        m = fmaxf(m, __shfl_xor(m, off, 64));
    }
    __shared__ float s8[8], m8[8];
    if ((t & 31) == 0) { s8[t >> 5] = s; m8[t >> 5] = m; }
    __syncthreads();
    if (t == 0) {
        float acc = 0.f;
        #pragma unroll
        for (int b2 = 0; b2 < BATCH; ++b2)
            acc += (s8[2 * b2] + s8[2 * b2 + 1]) * (1.f / NPTS)
                 + m8[2 * b2];                         // max only for pred2gt
        out[0] = acc * (1.f / BATCH);
    }
}

extern "C" void kernel_launch(void* const* d_in, const int* in_sizes, int n_in,
                              void* d_out, int out_size, void* d_ws, size_t ws_size,
                              hipStream_t stream) {
    const float* pred = (const float*)d_in[0];
    const float* gt   = (const float*)d_in[1];

    float2* partials = (float2*)d_ws;                  // 256 * 8 B = 2 KB

    dim3 g1(NXC, 1, 2 * BATCH);    // 32 x 1 x 8 = 256 blocks (1/CU)
    nn_fused<<<g1, TPB, 0, stream>>>(pred, gt, partials);
    reduce_all<<<dim3(1), 256, 0, stream>>>(partials, (float*)d_out);
}